// Round 1
// baseline (64.623 us; speedup 1.0000x reference)
//
#include <hip/hip_runtime.h>
#include <hip/hip_bf16.h>

typedef __attribute__((ext_vector_type(4))) float f32x4;
typedef __attribute__((ext_vector_type(8))) short bf16x8;
typedef __attribute__((ext_vector_type(4))) short bf16x4;

#define QS_STRIDE 68   // 64 + 4 pad, rows 272B (16B-aligned, conflict-light)
#define BT_STRIDE 72   // 64 + 8 pad, rows 144B (16B-aligned)

__device__ __forceinline__ short f2bf(float x) {
    union { float f; unsigned u; } v; v.f = x;
    unsigned r = (v.u + 0x7fffu + ((v.u >> 16) & 1u)) >> 16;  // RNE
    return (short)r;
}

__global__ __launch_bounds__(256) void quad_form_kernel(
    const float* __restrict__ q, const float* __restrict__ kv, float* __restrict__ out)
{
    __shared__ float qs[128 * QS_STRIDE];                       // 34816 B, q*0.125 fp32
    __shared__ __align__(16) unsigned short Bt[2][64 * BT_STRIDE]; // 18432 B, S slice bf16, [f][k]

    const int tid = threadIdx.x;

    // XCD-aware swizzle: both c-halves of a chunk land on the same XCD (b%8 round-robin)
    const int wg = blockIdx.x;            // 0..255
    const int x = wg & 7, p = wg >> 3;    // p: 0..31
    const int chunk = x * 16 + (p >> 1);  // 0..127  (= h*16 + n)
    const int half = p & 1;

    const float* qch = q   + (size_t)chunk * (256 * 64) + half * (128 * 64);
    const float* Sch = kv  + (size_t)chunk * 262144;            // 64*64*64
    float*       och = out + (size_t)chunk * (256 * 64) + half * (128 * 64);

    // ---- stage q half-chunk (128x64) into LDS as fp32, scaled by 1/8 (exact) ----
#pragma unroll
    for (int i = 0; i < 8; ++i) {
        int idx4 = i * 256 + tid;          // float4 index, 0..2047
        int row = idx4 >> 4;               // 16 float4 per 64-wide row
        int col = (idx4 & 15) << 2;
        f32x4 v = *(const f32x4*)(qch + idx4 * 4);
        v *= 0.125f;
        *(f32x4*)&qs[row * QS_STRIDE + col] = v;
    }

    // ---- staging mapping: thread -> (f = tid&63, k-quarter = tid>>6) ----
    const int fS = tid & 63;
    const int kq = tid >> 6;               // 0..3
    const float* Sbase = Sch + fS;

    float rA[16], rB[16];

    auto issue = [&](float* r, int d0) {
#pragma unroll
        for (int i = 0; i < 16; ++i)
            r[i] = Sbase[d0 * 4096 + (kq * 16 + i) * 64];  // coalesced dword loads
    };
    auto stage = [&](const float* r, int buf) {
#pragma unroll
        for (int i4 = 0; i4 < 4; ++i4) {
            bf16x4 wv;
#pragma unroll
            for (int j = 0; j < 4; ++j) wv[j] = f2bf(r[i4 * 4 + j]);
            *(bf16x4*)&Bt[buf][fS * BT_STRIDE + kq * 16 + i4 * 4] = wv;  // transposed [f][k]
        }
    };

    // ---- MFMA geometry: 4 waves, each 32 c-rows (2 M-tiles) x 64 f (4 N-tiles) ----
    const int lane = tid & 63;
    const int w = tid >> 6;
    const int lr0 = w * 32;
    const int ra = lane & 15;              // A row / B col within tile
    const int kg = lane >> 4;              // k-octet group

    f32x4 acc[2][4] = {};

    const float* qrow0 = qs + (lr0 + ra) * QS_STRIDE;
    const float* qrow1 = qs + (lr0 + 16 + ra) * QS_STRIDE;

    auto mfma_phase = [&](int buf, int d0) {
        float s0 = qrow0[d0];
        float s1 = qrow1[d0];
#pragma unroll
        for (int Ks = 0; Ks < 2; ++Ks) {
            int e0 = Ks * 32 + kg * 8;
            f32x4 u00 = *(const f32x4*)(qrow0 + e0);
            f32x4 u01 = *(const f32x4*)(qrow0 + e0 + 4);
            f32x4 u10 = *(const f32x4*)(qrow1 + e0);
            f32x4 u11 = *(const f32x4*)(qrow1 + e0 + 4);
            bf16x8 a0, a1;
#pragma unroll
            for (int j = 0; j < 4; ++j) {
                a0[j]     = f2bf(s0 * u00[j]);
                a0[j + 4] = f2bf(s0 * u01[j]);
                a1[j]     = f2bf(s1 * u10[j]);
                a1[j + 4] = f2bf(s1 * u11[j]);
            }
#pragma unroll
            for (int Nt = 0; Nt < 4; ++Nt) {
                bf16x8 b = *(const bf16x8*)&Bt[buf][(Nt * 16 + ra) * BT_STRIDE + e0];
                acc[0][Nt] = __builtin_amdgcn_mfma_f32_16x16x32_bf16(a0, b, acc[0][Nt], 0, 0, 0);
                acc[1][Nt] = __builtin_amdgcn_mfma_f32_16x16x32_bf16(a1, b, acc[1][Nt], 0, 0, 0);
            }
        }
    };

    // ---- K-loop over d0 slices, double-buffered LDS, loads 2 slices ahead ----
    issue(rA, 0);
    issue(rB, 1);
    for (int d0 = 0; d0 < 64; d0 += 2) {
        stage(rA, 0);
        if (d0 + 2 < 64) issue(rA, d0 + 2);
        __syncthreads();
        mfma_phase(0, d0);
        __syncthreads();

        stage(rB, 1);
        if (d0 + 3 < 64) issue(rB, d0 + 3);
        __syncthreads();
        mfma_phase(1, d0 + 1);
        __syncthreads();
    }

    // ---- epilogue: out = 0.5 * acc ----
#pragma unroll
    for (int Mt = 0; Mt < 2; ++Mt)
#pragma unroll
        for (int Nt = 0; Nt < 4; ++Nt)
#pragma unroll
            for (int j = 0; j < 4; ++j) {
                int r = lr0 + Mt * 16 + kg * 4 + j;
                och[r * 64 + Nt * 16 + ra] = 0.5f * acc[Mt][Nt][j];
            }
}

extern "C" void kernel_launch(void* const* d_in, const int* in_sizes, int n_in,
                              void* d_out, int out_size, void* d_ws, size_t ws_size,
                              hipStream_t stream) {
    const float* q  = (const float*)d_in[0];
    const float* kv = (const float*)d_in[1];
    float* out = (float*)d_out;
    hipLaunchKernelGGL(quad_form_kernel, dim3(256), dim3(256), 0, stream, q, kv, out);
}